// Round 6
// baseline (165.742 us; speedup 1.0000x reference)
//
#include <hip/hip_runtime.h>
#include <math.h>

#define DELTA 0.1f
constexpr int BLOCK = 256;
constexpr int RPT   = 5;   // 4,000,000 rows = 3125 blocks * 256 thr * 5 (exact)

// Keep-alive: scalar components only (gfx950 clang rejects vector "v" operands).
#define KEEP4(v) "v"((v).x), "v"((v).y), "v"((v).z), "v"((v).w)

__device__ __forceinline__ float row_loss(float4 p, float4 t) {
    float mp = (p.x + p.y + p.z + p.w) * 0.25f;
    float mt = (t.x + t.y + t.z + t.w) * 0.25f;
    float dpx = p.x - mp, dpy = p.y - mp, dpz = p.z - mp, dpw = p.w - mp;
    float dtx = t.x - mt, dty = t.y - mt, dtz = t.z - mt, dtw = t.w - mt;
    const float inv = 1.0f / 3.0f;  // 1/(D-1)
    float vp  = (dpx*dpx + dpy*dpy + dpz*dpz + dpw*dpw) * inv;
    float vt  = (dtx*dtx + dty*dty + dtz*dtz + dtw*dtw) * inv;
    float cov = (dpx*dtx + dpy*dty + dpz*dtz + dpw*dtw) * inv;
    float a1 = 2.0f * mp * mt + DELTA;
    float a2 = 2.0f * cov + DELTA;
    float b1 = mp * mp + mt * mt + DELTA;
    float b2 = vp + vt + DELTA;
    return 1.0f - (a1 * a2) / (b1 * b2 + DELTA);
}

__device__ __forceinline__ float block_reduce(float local, int tid) {
    #pragma unroll
    for (int off = 32; off > 0; off >>= 1)
        local += __shfl_down(local, off, 64);
    __shared__ float wsum[BLOCK / 64];
    int lane = tid & 63, wid = tid >> 6;
    if (lane == 0) wsum[wid] = local;
    __syncthreads();
    return wsum[0] + wsum[1] + wsum[2] + wsum[3];  // valid for tid 0
}

// Kernel A (main): all 10 loads' results forced live simultaneously via
// scalar keep-alive asm -> compiler cannot re-serialize to 2-deep.
__global__ __launch_bounds__(BLOCK) void ssim_partial_kernel(
    const float4* __restrict__ pred,
    const float4* __restrict__ target,
    float* __restrict__ partials,
    int N)
{
    const int tid  = threadIdx.x;
    const int base = blockIdx.x * (BLOCK * RPT);
    float local = 0.0f;

    if (base + BLOCK * RPT <= N) {  // uniform; exact at the bench shape
        const float4* pp = pred   + base + tid;
        const float4* tt = target + base + tid;
        float4 p0 = pp[0],         p1 = pp[BLOCK],     p2 = pp[2 * BLOCK],
               p3 = pp[3 * BLOCK], p4 = pp[4 * BLOCK];
        float4 t0 = tt[0],         t1 = tt[BLOCK],     t2 = tt[2 * BLOCK],
               t3 = tt[3 * BLOCK], t4 = tt[4 * BLOCK];
        asm volatile("" :: KEEP4(p0), KEEP4(p1), KEEP4(p2), KEEP4(p3), KEEP4(p4));
        asm volatile("" :: KEEP4(t0), KEEP4(t1), KEEP4(t2), KEEP4(t3), KEEP4(t4));
        local = row_loss(p0, t0) + row_loss(p1, t1) + row_loss(p2, t2)
              + row_loss(p3, t3) + row_loss(p4, t4);
    } else {
        for (int r = base + tid; r < N; r += BLOCK)
            local += row_loss(pred[r], target[r]);
    }

    float s = block_reduce(local, tid);
    if (tid == 0) partials[blockIdx.x] = s;
}

// Kernel B (probe, ws-only): read-ceiling microbench, 8 float4 in flight.
__global__ __launch_bounds__(BLOCK) void read_probe_kernel(
    const float4* __restrict__ a,
    const float4* __restrict__ b,
    float* __restrict__ sink,
    int n)
{
    const int tid = threadIdx.x;
    const int S   = gridDim.x * BLOCK;
    int i = blockIdx.x * BLOCK + tid;
    float acc = 0.0f;

    for (; i + 3 * S < n; i += 4 * S) {
        float4 a0 = a[i], a1 = a[i + S], a2 = a[i + 2 * S], a3 = a[i + 3 * S];
        float4 b0 = b[i], b1 = b[i + S], b2 = b[i + 2 * S], b3 = b[i + 3 * S];
        asm volatile("" :: KEEP4(a0), KEEP4(a1), KEEP4(a2), KEEP4(a3));
        asm volatile("" :: KEEP4(b0), KEEP4(b1), KEEP4(b2), KEEP4(b3));
        acc += (a0.x + a0.y + a0.z + a0.w) + (a1.x + a1.y + a1.z + a1.w)
             + (a2.x + a2.y + a2.z + a2.w) + (a3.x + a3.y + a3.z + a3.w)
             + (b0.x + b0.y + b0.z + b0.w) + (b1.x + b1.y + b1.z + b1.w)
             + (b2.x + b2.y + b2.z + b2.w) + (b3.x + b3.y + b3.z + b3.w);
    }
    for (; i < n; i += S) {
        float4 a0 = a[i], b0 = b[i];
        acc += a0.x + a0.y + a0.z + a0.w + b0.x + b0.y + b0.z + b0.w;
    }

    float s = block_reduce(acc, tid);
    if (tid == 0) sink[blockIdx.x] = s;
}

__global__ __launch_bounds__(BLOCK) void ssim_finalize_kernel(
    const float* __restrict__ partials, int nparts,
    float* __restrict__ out, int N)
{
    double local = 0.0;
    for (int i = threadIdx.x; i < nparts; i += BLOCK)
        local += (double)partials[i];

    #pragma unroll
    for (int off = 32; off > 0; off >>= 1)
        local += __shfl_down(local, off, 64);

    __shared__ double wave_sums[BLOCK / 64];
    int lane = threadIdx.x & 63;
    int wid  = threadIdx.x >> 6;
    if (lane == 0) wave_sums[wid] = local;
    __syncthreads();

    if (threadIdx.x == 0) {
        double total = wave_sums[0] + wave_sums[1] + wave_sums[2] + wave_sums[3];
        float f = (float)(total / (double)N);
        if (isnan(f)) f = 1.0f;   // reference NaN fallback == mean(ones) == 1.0
        *out = f;
    }
}

extern "C" void kernel_launch(void* const* d_in, const int* in_sizes, int n_in,
                              void* d_out, int out_size, void* d_ws, size_t ws_size,
                              hipStream_t stream)
{
    const float4* pred   = (const float4*)d_in[0];
    const float4* target = (const float4*)d_in[1];
    int rows = in_sizes[0] / 4;

    int grid = (rows + BLOCK * RPT - 1) / (BLOCK * RPT);  // 3125 at 4M rows
    if (grid < 1) grid = 1;

    float* partials = (float*)d_ws;                       // A's result
    float* sink     = (float*)((char*)d_ws + (64 << 10)); // B's sink (unused)

    // A first so its cache state is representative (post-restore); B is a
    // one-round instrument and will be deleted once it answers the question.
    ssim_partial_kernel<<<grid, BLOCK, 0, stream>>>(pred, target, partials, rows);
    read_probe_kernel<<<2048, BLOCK, 0, stream>>>(pred, target, sink, rows);
    ssim_finalize_kernel<<<1, BLOCK, 0, stream>>>(partials, grid, (float*)d_out, rows);
}

// Round 8
// 164.869 us; speedup vs baseline: 1.0053x; 1.0053x over previous
//
#include <hip/hip_runtime.h>
#include <math.h>

#define DELTA 0.1f
constexpr int BLOCK = 256;
constexpr int GRID  = 2048;   // persistent: 8 blocks/CU, waves loop over batches

// Keep-alive: scalar components (gfx950 clang rejects vector "v" operands).
#define KEEP4(v) "v"((v).x), "v"((v).y), "v"((v).z), "v"((v).w)

__device__ __forceinline__ float row_loss(float4 p, float4 t) {
    float mp = (p.x + p.y + p.z + p.w) * 0.25f;
    float mt = (t.x + t.y + t.z + t.w) * 0.25f;
    float dpx = p.x - mp, dpy = p.y - mp, dpz = p.z - mp, dpw = p.w - mp;
    float dtx = t.x - mt, dty = t.y - mt, dtz = t.z - mt, dtw = t.w - mt;
    const float inv = 1.0f / 3.0f;  // 1/(D-1)
    float vp  = (dpx*dpx + dpy*dpy + dpz*dpz + dpw*dpw) * inv;
    float vt  = (dtx*dtx + dty*dty + dtz*dtz + dtw*dtw) * inv;
    float cov = (dpx*dtx + dpy*dty + dpz*dtz + dpw*dtw) * inv;
    float a1 = 2.0f * mp * mt + DELTA;
    float a2 = 2.0f * cov + DELTA;
    float b1 = mp * mp + mt * mt + DELTA;
    float b2 = vp + vt + DELTA;
    return 1.0f - (a1 * a2) / (b1 * b2 + DELTA);
}

__device__ __forceinline__ float block_reduce(float local, int tid) {
    #pragma unroll
    for (int off = 32; off > 0; off >>= 1)
        local += __shfl_down(local, off, 64);
    __shared__ float wsum[BLOCK / 64];
    int lane = tid & 63, wid = tid >> 6;
    if (lane == 0) wsum[wid] = local;
    __syncthreads();
    return wsum[0] + wsum[1] + wsum[2] + wsum[3];  // valid for tid 0
}

// Main kernel in the probe's proven structure: persistent grid-stride,
// 8 float4 in flight per iteration, compute fused behind the load batch.
__global__ __launch_bounds__(BLOCK) void ssim_partial_kernel(
    const float4* __restrict__ pred,
    const float4* __restrict__ target,
    float* __restrict__ partials,
    int N)
{
    const int tid = threadIdx.x;
    const int S   = gridDim.x * BLOCK;
    int i = blockIdx.x * BLOCK + tid;
    float local = 0.0f;

    for (; i + 3 * S < N; i += 4 * S) {
        float4 p0 = pred[i],         p1 = pred[i + S],
               p2 = pred[i + 2 * S], p3 = pred[i + 3 * S];
        float4 t0 = target[i],         t1 = target[i + S],
               t2 = target[i + 2 * S], t3 = target[i + 3 * S];
        asm volatile("" :: KEEP4(p0), KEEP4(p1), KEEP4(p2), KEEP4(p3));
        asm volatile("" :: KEEP4(t0), KEEP4(t1), KEEP4(t2), KEEP4(t3));
        local += row_loss(p0, t0) + row_loss(p1, t1)
               + row_loss(p2, t2) + row_loss(p3, t3);
    }
    for (; i < N; i += S)
        local += row_loss(pred[i], target[i]);

    float s = block_reduce(local, tid);
    if (tid == 0) partials[blockIdx.x] = s;
}

// Control probe (hot-L3 read ceiling); delete next round once A matches it.
__global__ __launch_bounds__(BLOCK) void read_probe_kernel(
    const float4* __restrict__ a,
    const float4* __restrict__ b,
    float* __restrict__ sink,
    int n)
{
    const int tid = threadIdx.x;
    const int S   = gridDim.x * BLOCK;
    int i = blockIdx.x * BLOCK + tid;
    float acc = 0.0f;

    for (; i + 3 * S < n; i += 4 * S) {
        float4 a0 = a[i], a1 = a[i + S], a2 = a[i + 2 * S], a3 = a[i + 3 * S];
        float4 b0 = b[i], b1 = b[i + S], b2 = b[i + 2 * S], b3 = b[i + 3 * S];
        asm volatile("" :: KEEP4(a0), KEEP4(a1), KEEP4(a2), KEEP4(a3));
        asm volatile("" :: KEEP4(b0), KEEP4(b1), KEEP4(b2), KEEP4(b3));
        acc += (a0.x + a0.y + a0.z + a0.w) + (a1.x + a1.y + a1.z + a1.w)
             + (a2.x + a2.y + a2.z + a2.w) + (a3.x + a3.y + a3.z + a3.w)
             + (b0.x + b0.y + b0.z + b0.w) + (b1.x + b1.y + b1.z + b1.w)
             + (b2.x + b2.y + b2.z + b2.w) + (b3.x + b3.y + b3.z + b3.w);
    }
    for (; i < n; i += S) {
        float4 a0 = a[i], b0 = b[i];
        acc += a0.x + a0.y + a0.z + a0.w + b0.x + b0.y + b0.z + b0.w;
    }

    float s = block_reduce(acc, tid);
    if (tid == 0) sink[blockIdx.x] = s;
}

__global__ __launch_bounds__(BLOCK) void ssim_finalize_kernel(
    const float* __restrict__ partials, int nparts,
    float* __restrict__ out, int N)
{
    double local = 0.0;
    for (int i = threadIdx.x; i < nparts; i += BLOCK)
        local += (double)partials[i];

    #pragma unroll
    for (int off = 32; off > 0; off >>= 1)
        local += __shfl_down(local, off, 64);

    __shared__ double wave_sums[BLOCK / 64];
    int lane = threadIdx.x & 63;
    int wid  = threadIdx.x >> 6;
    if (lane == 0) wave_sums[wid] = local;
    __syncthreads();

    if (threadIdx.x == 0) {
        double total = wave_sums[0] + wave_sums[1] + wave_sums[2] + wave_sums[3];
        float f = (float)(total / (double)N);
        if (isnan(f)) f = 1.0f;   // reference NaN fallback == mean(ones) == 1.0
        *out = f;
    }
}

extern "C" void kernel_launch(void* const* d_in, const int* in_sizes, int n_in,
                              void* d_out, int out_size, void* d_ws, size_t ws_size,
                              hipStream_t stream)
{
    const float4* pred   = (const float4*)d_in[0];
    const float4* target = (const float4*)d_in[1];
    int rows = in_sizes[0] / 4;

    float* partials = (float*)d_ws;                       // GRID * 4 B
    float* sink     = (float*)((char*)d_ws + (64 << 10)); // probe sink (unused)

    // A first (post-restore cache state); B after (hot-L3 control).
    ssim_partial_kernel<<<GRID, BLOCK, 0, stream>>>(pred, target, partials, rows);
    read_probe_kernel<<<GRID, BLOCK, 0, stream>>>(pred, target, sink, rows);
    ssim_finalize_kernel<<<1, BLOCK, 0, stream>>>(partials, GRID, (float*)d_out, rows);
}

// Round 10
// 137.087 us; speedup vs baseline: 1.2090x; 1.2027x over previous
//
#include <hip/hip_runtime.h>
#include <math.h>

#define DELTA 0.1f
constexpr int BLOCK = 256;
constexpr int GRID  = 2048;   // persistent: 8 blocks/CU

// clang ext_vector (works with __builtin_nontemporal_load, unlike struct float4)
typedef float f4 __attribute__((ext_vector_type(4)));

// Keep-alive: scalar components (gfx950 clang rejects vector "v" operands).
#define KEEP4(v) "v"((v).x), "v"((v).y), "v"((v).z), "v"((v).w)

__device__ __forceinline__ float row_loss(f4 p, f4 t) {
    float mp = (p.x + p.y + p.z + p.w) * 0.25f;
    float mt = (t.x + t.y + t.z + t.w) * 0.25f;
    float dpx = p.x - mp, dpy = p.y - mp, dpz = p.z - mp, dpw = p.w - mp;
    float dtx = t.x - mt, dty = t.y - mt, dtz = t.z - mt, dtw = t.w - mt;
    const float inv = 1.0f / 3.0f;  // 1/(D-1)
    float vp  = (dpx*dpx + dpy*dpy + dpz*dpz + dpw*dpw) * inv;
    float vt  = (dtx*dtx + dty*dty + dtz*dtz + dtw*dtw) * inv;
    float cov = (dpx*dtx + dpy*dty + dpz*dtz + dpw*dtw) * inv;
    float a1 = 2.0f * mp * mt + DELTA;
    float a2 = 2.0f * cov + DELTA;
    float b1 = mp * mp + mt * mt + DELTA;
    float b2 = vp + vt + DELTA;
    return 1.0f - (a1 * a2) / (b1 * b2 + DELTA);
}

__device__ __forceinline__ float block_reduce(float local, int tid) {
    #pragma unroll
    for (int off = 32; off > 0; off >>= 1)
        local += __shfl_down(local, off, 64);
    __shared__ float wsum[BLOCK / 64];
    int lane = tid & 63, wid = tid >> 6;
    if (lane == 0) wsum[wid] = local;
    __syncthreads();
    return wsum[0] + wsum[1] + wsum[2] + wsum[3];  // valid for tid 0
}

// Persistent grid-stride; ALL loads non-temporal (single-use streaming data:
// bypass L3 allocate/victim churn on the post-restore at-capacity cache).
__global__ __launch_bounds__(BLOCK) void ssim_partial_kernel(
    const f4* __restrict__ pred,
    const f4* __restrict__ target,
    float* __restrict__ partials,
    int N)
{
    const int tid = threadIdx.x;
    const int S   = gridDim.x * BLOCK;
    int i = blockIdx.x * BLOCK + tid;
    float local = 0.0f;

    for (; i + 3 * S < N; i += 4 * S) {
        f4 p0 = __builtin_nontemporal_load(pred + i);
        f4 p1 = __builtin_nontemporal_load(pred + i + S);
        f4 p2 = __builtin_nontemporal_load(pred + i + 2 * S);
        f4 p3 = __builtin_nontemporal_load(pred + i + 3 * S);
        f4 t0 = __builtin_nontemporal_load(target + i);
        f4 t1 = __builtin_nontemporal_load(target + i + S);
        f4 t2 = __builtin_nontemporal_load(target + i + 2 * S);
        f4 t3 = __builtin_nontemporal_load(target + i + 3 * S);
        asm volatile("" :: KEEP4(p0), KEEP4(p1), KEEP4(p2), KEEP4(p3));
        asm volatile("" :: KEEP4(t0), KEEP4(t1), KEEP4(t2), KEEP4(t3));
        local += row_loss(p0, t0) + row_loss(p1, t1)
               + row_loss(p2, t2) + row_loss(p3, t3);
    }
    for (; i < N; i += S) {
        f4 p0 = __builtin_nontemporal_load(pred + i);
        f4 t0 = __builtin_nontemporal_load(target + i);
        local += row_loss(p0, t0);
    }

    float s = block_reduce(local, tid);
    if (tid == 0) partials[blockIdx.x] = s;
}

__global__ __launch_bounds__(BLOCK) void ssim_finalize_kernel(
    const float* __restrict__ partials, int nparts,
    float* __restrict__ out, int N)
{
    double local = 0.0;
    for (int i = threadIdx.x; i < nparts; i += BLOCK)
        local += (double)partials[i];

    #pragma unroll
    for (int off = 32; off > 0; off >>= 1)
        local += __shfl_down(local, off, 64);

    __shared__ double wave_sums[BLOCK / 64];
    int lane = threadIdx.x & 63;
    int wid  = threadIdx.x >> 6;
    if (lane == 0) wave_sums[wid] = local;
    __syncthreads();

    if (threadIdx.x == 0) {
        double total = wave_sums[0] + wave_sums[1] + wave_sums[2] + wave_sums[3];
        float f = (float)(total / (double)N);
        if (isnan(f)) f = 1.0f;   // reference NaN fallback == mean(ones) == 1.0
        *out = f;
    }
}

extern "C" void kernel_launch(void* const* d_in, const int* in_sizes, int n_in,
                              void* d_out, int out_size, void* d_ws, size_t ws_size,
                              hipStream_t stream)
{
    const f4* pred   = (const f4*)d_in[0];
    const f4* target = (const f4*)d_in[1];
    int rows = in_sizes[0] / 4;

    float* partials = (float*)d_ws;  // GRID * 4 B; every slot overwritten each call

    ssim_partial_kernel<<<GRID, BLOCK, 0, stream>>>(pred, target, partials, rows);
    ssim_finalize_kernel<<<1, BLOCK, 0, stream>>>(partials, GRID, (float*)d_out, rows);
}